// Round 6
// baseline (201.175 us; speedup 1.0000x reference)
//
#include <hip/hip_runtime.h>
#include <cstdint>

// 1 = fast transcendentals. Set 0 to restore libm path if arcs flip.
#ifndef FASTMATH
#define FASTMATH 1
#endif

#define NT 256

__device__ __forceinline__ uint32_t rotl32_(uint32_t v, int d) {
  return (v << d) | (v >> (32 - d));
}

// Threefry-2x32, 20 rounds, JAX partitionable-mode semantics.
__device__ __forceinline__ void tf2x32(uint32_t k0, uint32_t k1,
                                       uint32_t x0, uint32_t x1,
                                       uint32_t& o0, uint32_t& o1) {
  const uint32_t k2 = k0 ^ k1 ^ 0x1BD11BDAu;
  x0 += k0; x1 += k1;
#define TF4(a,b,c,d) \
  x0 += x1; x1 = rotl32_(x1,a); x1 ^= x0; \
  x0 += x1; x1 = rotl32_(x1,b); x1 ^= x0; \
  x0 += x1; x1 = rotl32_(x1,c); x1 ^= x0; \
  x0 += x1; x1 = rotl32_(x1,d); x1 ^= x0;
  TF4(13,15,26,6)
  x0 += k1; x1 += k2 + 1u;
  TF4(17,29,16,24)
  x0 += k2; x1 += k0 + 2u;
  TF4(13,15,26,6)
  x0 += k0; x1 += k1 + 3u;
  TF4(17,29,16,24)
  x0 += k1; x1 += k2 + 4u;
  TF4(13,15,26,6)
  x0 += k2; x1 += k0 + 5u;
#undef TF4
  o0 = x0; o1 = x1;
}

#if FASTMATH
__device__ __forceinline__ float tanh_(float x) {
  float e = __expf(2.0f * x);
  return 1.0f - __fdividef(2.0f, e + 1.0f);
}
__device__ __forceinline__ float sig_(float x) {
  return __fdividef(1.0f, 1.0f + __expf(-x));
}
#define log_ __logf
#define exp_ __expf
#else
__device__ __forceinline__ float tanh_(float x) { return tanhf(x); }
__device__ __forceinline__ float sig_(float x) { return 0.5f * tanhf(0.5f * x) + 0.5f; }
#define log_ logf
#define exp_ expf
#endif

// DPP helpers (full row/bank masks, bound_ctrl=1). Pure lane permutes.
template <int CTRL>
__device__ __forceinline__ float dppf(float x) {
  return __int_as_float(__builtin_amdgcn_update_dpp(
      0, __float_as_int(x), CTRL, 0xF, 0xF, true));
}
template <int CTRL>
__device__ __forceinline__ int dppi(int x) {
  return __builtin_amdgcn_update_dpp(0, x, CTRL, 0xF, 0xF, true);
}
constexpr int QP1 = 0xB1;   // quad_perm [1,0,3,2] : lane^1
constexpr int QP2 = 0x4E;   // quad_perm [2,3,0,1] : lane^2
constexpr int HM  = 0x141;  // row_half_mirror     : lane^7

__device__ __forceinline__ float rl(float v, int l) {
  return __int_as_float(__builtin_amdgcn_readlane(__float_as_int(v), l));
}

__global__ __launch_bounds__(NT, 1)
void nas_controller(const float* __restrict__ embed,
                    const float* __restrict__ w_ih,
                    const float* __restrict__ w_hh,
                    const float* __restrict__ b_ih,
                    const float* __restrict__ b_hh,
                    const float* __restrict__ w_soft,
                    const float* __restrict__ b_soft,
                    const float* __restrict__ b_soft_nl,
                    const float* __restrict__ w_attn1,
                    const float* __restrict__ w_attn2,
                    const float* __restrict__ v_attn,
                    const int* __restrict__ seedp,
                    float* __restrict__ out) {
  const int tid  = threadIdx.x;
  const int lane = tid & 63;
  const int wid  = tid >> 6;

  __shared__ __align__(16) float attn1L[4096];   // 64x16 float4, XOR-swizzled
  __shared__ __align__(16) float attn2L[4096];
  __shared__ __align__(16) float wgoL[8192];     // W_hh gates g,o (128 rows), swizzled
  __shared__ __align__(16) float wihL[16384];    // W_ih all 4 gates (256 rows), swizzled
  __shared__ __align__(16) float wsoftL[8 * 68]; // padded rows (bank spread)
  __shared__ __align__(16) float vaL[64];
  __shared__ __align__(16) float preL[13 * 256]; // float4 (i,f,g,o) per (slot,unit)
  __shared__ __align__(16) float aw1sL[8 * 68];  // anchor attn1 products (padded)
  __shared__ __align__(16) float hw2L[64];
  __shared__ __align__(16) float hB[64];         // h state (broadcast-read)
  __shared__ float gL[320];                      // precomputed gumbels
  __shared__ float bsoftL[8], bnlL[8];

  // ---- wave 0: issue W_hh i,f register loads early (latency hidden) ----
  float4 wri[16], wrf[16];
  if (wid == 0) {
    const float4* p = reinterpret_cast<const float4*>(w_hh);
#pragma unroll
    for (int k = 0; k < 16; ++k) {
      wri[k] = p[(0 * 64 + lane) * 16 + k];
      wrf[k] = p[(1 * 64 + lane) * 16 + k];
    }
  }

  // ---- staging (all 4 waves) ----
  {
    const float4* g1 = reinterpret_cast<const float4*>(w_attn1);
    const float4* g2 = reinterpret_cast<const float4*>(w_attn2);
    float4* l1 = reinterpret_cast<float4*>(attn1L);
    float4* l2 = reinterpret_cast<float4*>(attn2L);
    for (int i4 = tid; i4 < 1024; i4 += NT) {
      int r = i4 >> 4, c4 = i4 & 15, d = (i4 & ~15) + (c4 ^ (r & 15));
      l1[d] = g1[i4];
      l2[d] = g2[i4];
    }
    const float4* gih = reinterpret_cast<const float4*>(w_ih);
    float4* lih = reinterpret_cast<float4*>(wihL);
    for (int i4 = tid; i4 < 4096; i4 += NT) {
      int r = i4 >> 4, c4 = i4 & 15, d = (i4 & ~15) + (c4 ^ (r & 15));
      lih[d] = gih[i4];
    }
    const float4* ghh = reinterpret_cast<const float4*>(w_hh);
    float4* lgo = reinterpret_cast<float4*>(wgoL);
    for (int i4 = tid; i4 < 2048; i4 += NT) {   // g,o = global rows 128..255
      int r = i4 >> 4, c4 = i4 & 15, d = (i4 & ~15) + (c4 ^ (r & 15));
      lgo[d] = ghh[2048 + i4];
    }
  }
  for (int i = tid; i < 544; i += NT) {
    int r = i / 68, c = i % 68;
    wsoftL[i] = (r < 5 && c < 64) ? w_soft[r * 64 + c] : 0.f;
  }
  if (tid < 64) { vaL[tid] = v_attn[tid]; hB[tid] = 0.f; }
  if (tid < 8) {
    bsoftL[tid] = (tid < 5) ? b_soft[tid] : 0.f;
    bnlL[tid]   = (tid < 5) ? b_soft_nl[tid] : 0.f;
  }
  for (int i = tid; i < 512; i += NT) preL[6 * 256 + i] = 0.f;  // anchor slots 6,7 = 0

  // Gumbels for all 2x20x8 candidates (data-independent, off the chain).
  for (int t = tid; t < 320; t += NT) {
    int s_ = (t >= 160) ? 1 : 0;
    int rem = t - s_ * 160;
    int k = rem >> 3, i = rem & 7;
    uint32_t a, b, ka, kb, o0, o1;
    tf2x32(0u, (uint32_t)seedp[0], 0u, (uint32_t)s_, a, b);  // split(root)[s]
    tf2x32(a, b, 0u, (uint32_t)k, ka, kb);                   // split(k_s,20)[k]
    tf2x32(ka, kb, 0u, (uint32_t)i, o0, o1);                 // random_bits
    uint32_t bits = o0 ^ o1;
    const float TINY = 1.1754943508222875e-38f;
    float uu = __uint_as_float((bits >> 9) | 0x3f800000u) - 1.0f;
    uu = uu * (1.0f - TINY) + TINY;
    uu = fmaxf(TINY, uu);
    gL[t] = -log_(-log_(uu));
  }

  __syncthreads();

  // W_ih @ embed[e] for slots 0..5, from LDS (bounded transient registers).
  for (int e = wid; e < 6; e += 4) {
    float ew = embed[e * 64 + lane];
    const float4* q = reinterpret_cast<const float4*>(wihL);
    float ai = 0, af = 0, ag = 0, ao = 0;
#pragma unroll 4
    for (int c4 = 0; c4 < 16; ++c4) {
      int sw = (lane << 4) + (c4 ^ (lane & 15));
      float4 wiv = q[sw], wfv = q[(64 << 4) + sw],
             wgv = q[(128 << 4) + sw], wov = q[(192 << 4) + sw];
      float s0 = rl(ew, 4 * c4), s1 = rl(ew, 4 * c4 + 1),
            s2 = rl(ew, 4 * c4 + 2), s3 = rl(ew, 4 * c4 + 3);
      ai = fmaf(wiv.x, s0, ai); ai = fmaf(wiv.y, s1, ai);
      ai = fmaf(wiv.z, s2, ai); ai = fmaf(wiv.w, s3, ai);
      af = fmaf(wfv.x, s0, af); af = fmaf(wfv.y, s1, af);
      af = fmaf(wfv.z, s2, af); af = fmaf(wfv.w, s3, af);
      ag = fmaf(wgv.x, s0, ag); ag = fmaf(wgv.y, s1, ag);
      ag = fmaf(wgv.z, s2, ag); ag = fmaf(wgv.w, s3, ag);
      ao = fmaf(wov.x, s0, ao); ao = fmaf(wov.y, s1, ao);
      ao = fmaf(wov.z, s2, ao); ao = fmaf(wov.w, s3, ao);
    }
    reinterpret_cast<float4*>(preL)[e * 64 + lane] = make_float4(ai, af, ag, ao);
  }

  __syncthreads();
  if (wid != 0) return;       // single wave from here on; no more barriers

  const float bias_i = b_ih[lane] + b_hh[lane];
  const float bias_f = b_ih[64 + lane] + b_hh[64 + lane];
  const float bias_g = b_ih[128 + lane] + b_hh[128 + lane];
  const float bias_o = b_ih[192 + lane] + b_hh[192 + lane];

  float creg = 0.f, lp = 0.f, ent = 0.f;
  int srcSlot = 0, sIdx = 0;
  const float4* hU = reinterpret_cast<const float4*>(hB);  // uniform broadcast reads

  auto lstm = [&]() {
    float4 pre = reinterpret_cast<float4*>(preL)[srcSlot * 64 + lane];
    const float4* wg4 = reinterpret_cast<const float4*>(wgoL);
    float ai = 0, af = 0, ag = 0, ao = 0;
#pragma unroll
    for (int c4 = 0; c4 < 16; ++c4) {
      int sw = c4 ^ (lane & 15);
      float4 hv = hU[c4];                           // uniform-address broadcast
      float4 wiv = wri[c4], wfv = wrf[c4];
      float4 wgv = wg4[(lane << 4) + sw];           // g rows 0..63
      float4 wov = wg4[((64 + lane) << 4) + sw];    // o rows 64..127
      ai = fmaf(wiv.x, hv.x, ai); ai = fmaf(wiv.y, hv.y, ai);
      ai = fmaf(wiv.z, hv.z, ai); ai = fmaf(wiv.w, hv.w, ai);
      af = fmaf(wfv.x, hv.x, af); af = fmaf(wfv.y, hv.y, af);
      af = fmaf(wfv.z, hv.z, af); af = fmaf(wfv.w, hv.w, af);
      ag = fmaf(wgv.x, hv.x, ag); ag = fmaf(wgv.y, hv.y, ag);
      ag = fmaf(wgv.z, hv.z, ag); ag = fmaf(wgv.w, hv.w, ag);
      ao = fmaf(wov.x, hv.x, ao); ao = fmaf(wov.y, hv.y, ao);
      ao = fmaf(wov.z, hv.z, ao); ao = fmaf(wov.w, hv.w, ao);
    }
    float gi = ai + pre.x + bias_i, gf = af + pre.y + bias_f;
    float gg = ag + pre.z + bias_g, go = ao + pre.w + bias_o;
    float c2 = sig_(gf) * creg + sig_(gi) * tanh_(gg);
    float h2 = sig_(go) * tanh_(c2);
    creg = c2;
    hB[lane] = h2;                                  // distribute new h
  };

  // dst[lane] = dot(W[lane,:], h). Swizzled LDS weights, h broadcast reads.
  auto matvec = [&](const float* W) -> float {
    const float4* w4 = reinterpret_cast<const float4*>(W);
    float a0 = 0, a1 = 0, a2 = 0, a3 = 0;
#pragma unroll
    for (int c4 = 0; c4 < 16; ++c4) {
      float4 w = w4[(lane << 4) + (c4 ^ (lane & 15))];
      float4 hv = hU[c4];
      a0 = fmaf(w.x, hv.x, a0);
      a1 = fmaf(w.y, hv.y, a1);
      a2 = fmaf(w.z, hv.z, a2);
      a3 = fmaf(w.w, hv.w, a3);
    }
    return (a0 + a1) + (a2 + a3);
  };

  // W_ih @ h (new anchor) from LDS, bounded unroll (register transients).
  auto anchorPre = [&](int slot) {
    const float4* q = reinterpret_cast<const float4*>(wihL);
    float ai = 0, af = 0, ag = 0, ao = 0;
#pragma unroll 4
    for (int c4 = 0; c4 < 16; ++c4) {
      int sw = (lane << 4) + (c4 ^ (lane & 15));
      float4 wiv = q[sw], wfv = q[(64 << 4) + sw],
             wgv = q[(128 << 4) + sw], wov = q[(192 << 4) + sw];
      float4 hv = hU[c4];
      ai = fmaf(wiv.x, hv.x, ai); ai = fmaf(wiv.y, hv.y, ai);
      ai = fmaf(wiv.z, hv.z, ai); ai = fmaf(wiv.w, hv.w, ai);
      af = fmaf(wfv.x, hv.x, af); af = fmaf(wfv.y, hv.y, af);
      af = fmaf(wfv.z, hv.z, af); af = fmaf(wfv.w, hv.w, af);
      ag = fmaf(wgv.x, hv.x, ag); ag = fmaf(wgv.y, hv.y, ag);
      ag = fmaf(wgv.z, hv.z, ag); ag = fmaf(wgv.w, hv.w, ag);
      ao = fmaf(wov.x, hv.x, ao); ao = fmaf(wov.y, hv.y, ao);
      ao = fmaf(wov.z, hv.z, ao); ao = fmaf(wov.w, hv.w, ao);
    }
    reinterpret_cast<float4*>(preL)[slot * 64 + lane] = make_float4(ai, af, ag, ao);
  };

  // Gumbel-max categorical + log_prob/entropy. raw logit for candidate i in
  // lane i (lanes >= n ignored). Returns sampled index (uniform).
  auto doSample = [&](int n, int k, int mode, float raw, float* op) -> int {
    float l;
    if (lane < n) {
      if (mode == 0) l = raw / 5.0f + 1.1f * tanh_(raw);
      else {
        l = (float)(1.1 / 2.5) * tanh_(raw / 5.0f);
        if (mode == 1) l += bnlL[lane];
      }
    } else l = -INFINITY;
    float g = (lane < n) ? gL[sIdx * 160 + k * 8 + lane] : 0.f;
    float v = (lane < n) ? (l + g) : -INFINITY;
    int bi = lane & 7;
    float lw = l;
#define ARGSTEP(C) { float ov = dppf<C>(v), ol = dppf<C>(lw); int oi = dppi<C>(bi); \
    bool tk = (ov > v) || (ov == v && oi < bi); if (tk) { v = ov; lw = ol; bi = oi; } }
    ARGSTEP(QP1) ARGSTEP(QP2) ARGSTEP(HM)
#undef ARGSTEP
    float mx = l;
    mx = fmaxf(mx, dppf<QP1>(mx)); mx = fmaxf(mx, dppf<QP2>(mx)); mx = fmaxf(mx, dppf<HM>(mx));
    float e = (lane < n) ? exp_(l - mx) : 0.f;
    float ss = e; ss += dppf<QP1>(ss); ss += dppf<QP2>(ss); ss += dppf<HM>(ss);
    float lse = log_(ss);
    float lpi = l - mx - lse;
    float ec = (lane < n) ? lpi * exp_(lpi) : 0.f;
    ec += dppf<QP1>(ec); ec += dppf<QP2>(ec); ec += dppf<HM>(ec);
    if (lane == 0) {
      lp  += -(lw - mx - lse);
      ent += -ec;
      op[0] = (float)bi;
    }
    return __builtin_amdgcn_readfirstlane(bi);
  };

  for (int s = 0; s < 2; ++s) {
    sIdx = s;
    srcSlot = 0;
    for (int w = 0; w < 2; ++w) {                 // warmup anchors
      lstm();
      aw1sL[w * 68 + lane] = matvec(attn1L);
    }
    int keyk = 0;
    for (int L = 2; L <= 6; ++L) {
      for (int t = 0; t < 2; ++t) {               // 2 index samples
        lstm();
        hw2L[lane] = matvec(attn2L);
        const int r8 = lane >> 3, j = lane & 7;
        float sacc = 0.f;
        {
          const float4* aw = reinterpret_cast<const float4*>(aw1sL + r8 * 68 + j * 8);
          const float4* hq = reinterpret_cast<const float4*>(hw2L + j * 8);
          const float4* vq = reinterpret_cast<const float4*>(vaL + j * 8);
          float4 a0 = aw[0], a1 = aw[1], h0 = hq[0], h1 = hq[1], v0 = vq[0], v1 = vq[1];
          sacc = fmaf(tanh_(a0.x + h0.x), v0.x, sacc);
          sacc = fmaf(tanh_(a0.y + h0.y), v0.y, sacc);
          sacc = fmaf(tanh_(a0.z + h0.z), v0.z, sacc);
          sacc = fmaf(tanh_(a0.w + h0.w), v0.w, sacc);
          sacc = fmaf(tanh_(a1.x + h1.x), v1.x, sacc);
          sacc = fmaf(tanh_(a1.y + h1.y), v1.y, sacc);
          sacc = fmaf(tanh_(a1.z + h1.z), v1.z, sacc);
          sacc = fmaf(tanh_(a1.w + h1.w), v1.w, sacc);
        }
        sacc += dppf<QP1>(sacc); sacc += dppf<QP2>(sacc); sacc += dppf<HM>(sacc);
        float raw = __shfl(sacc, lane << 3);      // group sums -> lanes 0..7
        int sel = doSample(L, keyk, 0, raw, out + s * 20 + (L - 2) * 4 + t * 2);
        keyk++;
        srcSlot = 6 + sel;                        // x = anchors[index]
      }
      for (int t = 0; t < 2; ++t) {               // 2 op samples
        lstm();
        float a0 = 0, a1 = 0, a2 = 0, a3 = 0;
        const float4* wq = reinterpret_cast<const float4*>(wsoftL + (lane & 7) * 68);
#pragma unroll
        for (int c4 = 0; c4 < 16; ++c4) {
          float4 w = wq[c4];
          float4 hv = hU[c4];
          a0 = fmaf(w.x, hv.x, a0);
          a1 = fmaf(w.y, hv.y, a1);
          a2 = fmaf(w.z, hv.z, a2);
          a3 = fmaf(w.w, hv.w, a3);
        }
        float raw = (a0 + a1) + (a2 + a3) + bsoftL[lane & 7];
        int sel = doSample(5, keyk, (s == 0) ? 1 : 2, raw,
                           out + s * 20 + (L - 2) * 4 + t * 2 + 1);
        keyk++;
        srcSlot = 1 + sel;                        // x = embed[op+1]
      }
      lstm();                                     // anchor step
      aw1sL[L * 68 + lane] = matvec(attn1L);
      anchorPre(6 + L);
      srcSlot = 0;                                // x = embed[0]
    }
  }

  if (lane == 0) { out[40] = lp; out[41] = ent; }
}

extern "C" void kernel_launch(void* const* d_in, const int* in_sizes, int n_in,
                              void* d_out, int out_size, void* d_ws, size_t ws_size,
                              hipStream_t stream) {
  (void)in_sizes; (void)n_in; (void)out_size; (void)d_ws; (void)ws_size;
  nas_controller<<<1, NT, 0, stream>>>(
      (const float*)d_in[0],  // embed
      (const float*)d_in[1],  // w_ih
      (const float*)d_in[2],  // w_hh
      (const float*)d_in[3],  // b_ih
      (const float*)d_in[4],  // b_hh
      (const float*)d_in[5],  // w_soft
      (const float*)d_in[6],  // b_soft
      (const float*)d_in[7],  // b_soft_no_learn
      (const float*)d_in[8],  // w_attn1
      (const float*)d_in[9],  // w_attn2
      (const float*)d_in[10], // v_attn
      (const int*)d_in[11],   // seed
      (float*)d_out);
}

// Round 7
// 160.116 us; speedup vs baseline: 1.2564x; 1.2564x over previous
//
#include <hip/hip_runtime.h>
#include <cstdint>

// 1 = fast transcendentals. Set 0 to restore libm path if arcs flip.
#ifndef FASTMATH
#define FASTMATH 1
#endif

#define NT 256

__device__ __forceinline__ uint32_t rotl32_(uint32_t v, int d) {
  return (v << d) | (v >> (32 - d));
}

// Threefry-2x32, 20 rounds, JAX partitionable-mode semantics.
__device__ __forceinline__ void tf2x32(uint32_t k0, uint32_t k1,
                                       uint32_t x0, uint32_t x1,
                                       uint32_t& o0, uint32_t& o1) {
  const uint32_t k2 = k0 ^ k1 ^ 0x1BD11BDAu;
  x0 += k0; x1 += k1;
#define TF4(a,b,c,d) \
  x0 += x1; x1 = rotl32_(x1,a); x1 ^= x0; \
  x0 += x1; x1 = rotl32_(x1,b); x1 ^= x0; \
  x0 += x1; x1 = rotl32_(x1,c); x1 ^= x0; \
  x0 += x1; x1 = rotl32_(x1,d); x1 ^= x0;
  TF4(13,15,26,6)
  x0 += k1; x1 += k2 + 1u;
  TF4(17,29,16,24)
  x0 += k2; x1 += k0 + 2u;
  TF4(13,15,26,6)
  x0 += k0; x1 += k1 + 3u;
  TF4(17,29,16,24)
  x0 += k1; x1 += k2 + 4u;
  TF4(13,15,26,6)
  x0 += k2; x1 += k0 + 5u;
#undef TF4
  o0 = x0; o1 = x1;
}

#if FASTMATH
__device__ __forceinline__ float tanh_(float x) {
  float e = __expf(2.0f * x);
  return 1.0f - __fdividef(2.0f, e + 1.0f);
}
__device__ __forceinline__ float sig_(float x) {
  return __fdividef(1.0f, 1.0f + __expf(-x));
}
#define log_ __logf
#define exp_ __expf
#else
__device__ __forceinline__ float tanh_(float x) { return tanhf(x); }
__device__ __forceinline__ float sig_(float x) { return 0.5f * tanhf(0.5f * x) + 0.5f; }
#define log_ logf
#define exp_ expf
#endif

// DPP helpers (full row/bank masks, bound_ctrl=1). Pure lane permutes.
template <int CTRL>
__device__ __forceinline__ float dppf(float x) {
  return __int_as_float(__builtin_amdgcn_update_dpp(
      0, __float_as_int(x), CTRL, 0xF, 0xF, true));
}
template <int CTRL>
__device__ __forceinline__ int dppi(int x) {
  return __builtin_amdgcn_update_dpp(0, x, CTRL, 0xF, 0xF, true);
}
constexpr int QP1 = 0xB1;   // quad_perm [1,0,3,2] : lane^1
constexpr int QP2 = 0x4E;   // quad_perm [2,3,0,1] : lane^2
constexpr int HM  = 0x141;  // row_half_mirror     : lane^7

__device__ __forceinline__ float rl(float v, int l) {
  return __int_as_float(__builtin_amdgcn_readlane(__float_as_int(v), l));
}

__global__ __launch_bounds__(NT, 1)
void nas_controller(const float* __restrict__ embed,
                    const float* __restrict__ w_ih,
                    const float* __restrict__ w_hh,
                    const float* __restrict__ b_ih,
                    const float* __restrict__ b_hh,
                    const float* __restrict__ w_soft,
                    const float* __restrict__ b_soft,
                    const float* __restrict__ b_soft_nl,
                    const float* __restrict__ w_attn1,
                    const float* __restrict__ w_attn2,
                    const float* __restrict__ v_attn,
                    const int* __restrict__ seedp,
                    float* __restrict__ out) {
  const int tid  = threadIdx.x;
  const int lane = tid & 63;
  const int wid  = tid >> 6;

  __shared__ __align__(16) float whhL[16384];    // all 4 W_hh gates, swizzled (64KB)
  __shared__ __align__(16) float attn1L[4096];   // 64x16 float4, XOR-swizzled
  __shared__ __align__(16) float attn2L[4096];
  __shared__ __align__(16) float wsoftL[8 * 68]; // padded rows (bank spread)
  __shared__ __align__(16) float vaL[64];
  __shared__ __align__(16) float preL[13 * 256]; // float4 (i,f,g,o) per (slot,unit)
  __shared__ __align__(16) float aw1sL[8 * 68];  // anchor attn1 products (padded)
  __shared__ __align__(16) float hw2L[64];
  __shared__ __align__(16) float hB[64];         // h state (broadcast-read)
  __shared__ float gL[320];                      // precomputed gumbels
  __shared__ float bsoftL[8], bnlL[8];

  // ---- staging (all 4 waves); NO persistent register arrays anywhere ----
  {
    const float4* ghh = reinterpret_cast<const float4*>(w_hh);
    float4* lhh = reinterpret_cast<float4*>(whhL);
    for (int i4 = tid; i4 < 4096; i4 += NT) {
      int r = i4 >> 4, c4 = i4 & 15, d = (i4 & ~15) + (c4 ^ (r & 15));
      lhh[d] = ghh[i4];
    }
    const float4* g1 = reinterpret_cast<const float4*>(w_attn1);
    const float4* g2 = reinterpret_cast<const float4*>(w_attn2);
    float4* l1 = reinterpret_cast<float4*>(attn1L);
    float4* l2 = reinterpret_cast<float4*>(attn2L);
    for (int i4 = tid; i4 < 1024; i4 += NT) {
      int r = i4 >> 4, c4 = i4 & 15, d = (i4 & ~15) + (c4 ^ (r & 15));
      l1[d] = g1[i4];
      l2[d] = g2[i4];
    }
  }
  for (int i = tid; i < 544; i += NT) {
    int r = i / 68, c = i % 68;
    wsoftL[i] = (r < 5 && c < 64) ? w_soft[r * 64 + c] : 0.f;
  }
  if (tid < 64) { vaL[tid] = v_attn[tid]; hB[tid] = 0.f; }
  if (tid < 8) {
    bsoftL[tid] = (tid < 5) ? b_soft[tid] : 0.f;
    bnlL[tid]   = (tid < 5) ? b_soft_nl[tid] : 0.f;
  }
  for (int i = tid; i < 512; i += NT) preL[6 * 256 + i] = 0.f;  // anchor slots 6,7 = 0

  // Gumbels for all 2x20x8 candidates (data-independent, off the chain).
  for (int t = tid; t < 320; t += NT) {
    int s_ = (t >= 160) ? 1 : 0;
    int rem = t - s_ * 160;
    int k = rem >> 3, i = rem & 7;
    uint32_t a, b, ka, kb, o0, o1;
    tf2x32(0u, (uint32_t)seedp[0], 0u, (uint32_t)s_, a, b);  // split(root)[s]
    tf2x32(a, b, 0u, (uint32_t)k, ka, kb);                   // split(k_s,20)[k]
    tf2x32(ka, kb, 0u, (uint32_t)i, o0, o1);                 // random_bits
    uint32_t bits = o0 ^ o1;
    const float TINY = 1.1754943508222875e-38f;
    float uu = __uint_as_float((bits >> 9) | 0x3f800000u) - 1.0f;
    uu = uu * (1.0f - TINY) + TINY;
    uu = fmaxf(TINY, uu);
    gL[t] = -log_(-log_(uu));
  }

  // W_ih @ embed[e] for slots 0..5 from GLOBAL (4 waves split; off the chain).
  for (int e = wid; e < 6; e += 4) {
    float ew = embed[e * 64 + lane];
    const float4* q = reinterpret_cast<const float4*>(w_ih);
    float ai = 0, af = 0, ag = 0, ao = 0;
#pragma unroll 2
    for (int c4 = 0; c4 < 16; ++c4) {
      float4 wiv = q[(0 * 64 + lane) * 16 + c4], wfv = q[(1 * 64 + lane) * 16 + c4],
             wgv = q[(2 * 64 + lane) * 16 + c4], wov = q[(3 * 64 + lane) * 16 + c4];
      float s0 = rl(ew, 4 * c4), s1 = rl(ew, 4 * c4 + 1),
            s2 = rl(ew, 4 * c4 + 2), s3 = rl(ew, 4 * c4 + 3);
      ai = fmaf(wiv.x, s0, ai); ai = fmaf(wiv.y, s1, ai);
      ai = fmaf(wiv.z, s2, ai); ai = fmaf(wiv.w, s3, ai);
      af = fmaf(wfv.x, s0, af); af = fmaf(wfv.y, s1, af);
      af = fmaf(wfv.z, s2, af); af = fmaf(wfv.w, s3, af);
      ag = fmaf(wgv.x, s0, ag); ag = fmaf(wgv.y, s1, ag);
      ag = fmaf(wgv.z, s2, ag); ag = fmaf(wgv.w, s3, ag);
      ao = fmaf(wov.x, s0, ao); ao = fmaf(wov.y, s1, ao);
      ao = fmaf(wov.z, s2, ao); ao = fmaf(wov.w, s3, ao);
    }
    reinterpret_cast<float4*>(preL)[e * 64 + lane] = make_float4(ai, af, ag, ao);
  }

  __syncthreads();
  if (wid != 0) return;       // single wave from here on; no more barriers

  const float bias_i = b_ih[lane] + b_hh[lane];
  const float bias_f = b_ih[64 + lane] + b_hh[64 + lane];
  const float bias_g = b_ih[128 + lane] + b_hh[128 + lane];
  const float bias_o = b_ih[192 + lane] + b_hh[192 + lane];

  float creg = 0.f, lp = 0.f, ent = 0.f;
  int srcSlot = 0, sIdx = 0;
  const float4* hU = reinterpret_cast<const float4*>(hB);  // uniform broadcast reads

  auto lstm = [&]() {
    float4 pre = reinterpret_cast<float4*>(preL)[srcSlot * 64 + lane];
    const float4* w4 = reinterpret_cast<const float4*>(whhL);
    float ai = 0, af = 0, ag = 0, ao = 0;
#pragma unroll 4
    for (int c4 = 0; c4 < 16; ++c4) {
      int sw = c4 ^ (lane & 15);
      float4 hv = hU[c4];                               // uniform-address broadcast
      float4 wiv = w4[(lane << 4) + sw];                // i rows 0..63
      float4 wfv = w4[((64 + lane) << 4) + sw];         // f rows 64..127
      float4 wgv = w4[((128 + lane) << 4) + sw];        // g rows 128..191
      float4 wov = w4[((192 + lane) << 4) + sw];        // o rows 192..255
      ai = fmaf(wiv.x, hv.x, ai); ai = fmaf(wiv.y, hv.y, ai);
      ai = fmaf(wiv.z, hv.z, ai); ai = fmaf(wiv.w, hv.w, ai);
      af = fmaf(wfv.x, hv.x, af); af = fmaf(wfv.y, hv.y, af);
      af = fmaf(wfv.z, hv.z, af); af = fmaf(wfv.w, hv.w, af);
      ag = fmaf(wgv.x, hv.x, ag); ag = fmaf(wgv.y, hv.y, ag);
      ag = fmaf(wgv.z, hv.z, ag); ag = fmaf(wgv.w, hv.w, ag);
      ao = fmaf(wov.x, hv.x, ao); ao = fmaf(wov.y, hv.y, ao);
      ao = fmaf(wov.z, hv.z, ao); ao = fmaf(wov.w, hv.w, ao);
    }
    float gi = ai + pre.x + bias_i, gf = af + pre.y + bias_f;
    float gg = ag + pre.z + bias_g, go = ao + pre.w + bias_o;
    float c2 = sig_(gf) * creg + sig_(gi) * tanh_(gg);
    float h2 = sig_(go) * tanh_(c2);
    creg = c2;
    hB[lane] = h2;                                      // distribute new h
  };

  // dst[lane] = dot(W[lane,:], h). Swizzled LDS weights, h broadcast reads.
  auto matvec = [&](const float* W) -> float {
    const float4* w4 = reinterpret_cast<const float4*>(W);
    float a0 = 0, a1 = 0, a2 = 0, a3 = 0;
#pragma unroll 4
    for (int c4 = 0; c4 < 16; ++c4) {
      float4 w = w4[(lane << 4) + (c4 ^ (lane & 15))];
      float4 hv = hU[c4];
      a0 = fmaf(w.x, hv.x, a0);
      a1 = fmaf(w.y, hv.y, a1);
      a2 = fmaf(w.z, hv.z, a2);
      a3 = fmaf(w.w, hv.w, a3);
    }
    return (a0 + a1) + (a2 + a3);
  };

  // W_ih @ h (new anchor) streamed from GLOBAL (L2-warm), bounded unroll.
  auto anchorPre = [&](int slot) {
    const float4* q = reinterpret_cast<const float4*>(w_ih);
    float ai = 0, af = 0, ag = 0, ao = 0;
#pragma unroll 4
    for (int c4 = 0; c4 < 16; ++c4) {
      float4 wiv = q[(0 * 64 + lane) * 16 + c4], wfv = q[(1 * 64 + lane) * 16 + c4],
             wgv = q[(2 * 64 + lane) * 16 + c4], wov = q[(3 * 64 + lane) * 16 + c4];
      float4 hv = hU[c4];
      ai = fmaf(wiv.x, hv.x, ai); ai = fmaf(wiv.y, hv.y, ai);
      ai = fmaf(wiv.z, hv.z, ai); ai = fmaf(wiv.w, hv.w, ai);
      af = fmaf(wfv.x, hv.x, af); af = fmaf(wfv.y, hv.y, af);
      af = fmaf(wfv.z, hv.z, af); af = fmaf(wfv.w, hv.w, af);
      ag = fmaf(wgv.x, hv.x, ag); ag = fmaf(wgv.y, hv.y, ag);
      ag = fmaf(wgv.z, hv.z, ag); ag = fmaf(wgv.w, hv.w, ag);
      ao = fmaf(wov.x, hv.x, ao); ao = fmaf(wov.y, hv.y, ao);
      ao = fmaf(wov.z, hv.z, ao); ao = fmaf(wov.w, hv.w, ao);
    }
    reinterpret_cast<float4*>(preL)[slot * 64 + lane] = make_float4(ai, af, ag, ao);
  };

  // Gumbel-max categorical + log_prob/entropy. raw logit for candidate i in
  // lane i (lanes >= n ignored). Returns sampled index (uniform).
  auto doSample = [&](int n, int k, int mode, float raw, float* op) -> int {
    float l;
    if (lane < n) {
      if (mode == 0) l = raw / 5.0f + 1.1f * tanh_(raw);
      else {
        l = (float)(1.1 / 2.5) * tanh_(raw / 5.0f);
        if (mode == 1) l += bnlL[lane];
      }
    } else l = -INFINITY;
    float g = (lane < n) ? gL[sIdx * 160 + k * 8 + lane] : 0.f;
    float v = (lane < n) ? (l + g) : -INFINITY;
    int bi = lane & 7;
    float lw = l;
#define ARGSTEP(C) { float ov = dppf<C>(v), ol = dppf<C>(lw); int oi = dppi<C>(bi); \
    bool tk = (ov > v) || (ov == v && oi < bi); if (tk) { v = ov; lw = ol; bi = oi; } }
    ARGSTEP(QP1) ARGSTEP(QP2) ARGSTEP(HM)
#undef ARGSTEP
    float mx = l;
    mx = fmaxf(mx, dppf<QP1>(mx)); mx = fmaxf(mx, dppf<QP2>(mx)); mx = fmaxf(mx, dppf<HM>(mx));
    float e = (lane < n) ? exp_(l - mx) : 0.f;
    float ss = e; ss += dppf<QP1>(ss); ss += dppf<QP2>(ss); ss += dppf<HM>(ss);
    float lse = log_(ss);
    float lpi = l - mx - lse;
    float ec = (lane < n) ? lpi * exp_(lpi) : 0.f;
    ec += dppf<QP1>(ec); ec += dppf<QP2>(ec); ec += dppf<HM>(ec);
    if (lane == 0) {
      lp  += -(lw - mx - lse);
      ent += -ec;
      op[0] = (float)bi;
    }
    return __builtin_amdgcn_readfirstlane(bi);
  };

  for (int s = 0; s < 2; ++s) {
    sIdx = s;
    srcSlot = 0;
    for (int w = 0; w < 2; ++w) {                 // warmup anchors
      lstm();
      aw1sL[w * 68 + lane] = matvec(attn1L);
    }
    int keyk = 0;
    for (int L = 2; L <= 6; ++L) {
      for (int t = 0; t < 2; ++t) {               // 2 index samples
        lstm();
        hw2L[lane] = matvec(attn2L);
        const int r8 = lane >> 3, j = lane & 7;
        float sacc = 0.f;
        {
          const float4* aw = reinterpret_cast<const float4*>(aw1sL + r8 * 68 + j * 8);
          const float4* hq = reinterpret_cast<const float4*>(hw2L + j * 8);
          const float4* vq = reinterpret_cast<const float4*>(vaL + j * 8);
          float4 a0 = aw[0], a1 = aw[1], h0 = hq[0], h1 = hq[1], v0 = vq[0], v1 = vq[1];
          sacc = fmaf(tanh_(a0.x + h0.x), v0.x, sacc);
          sacc = fmaf(tanh_(a0.y + h0.y), v0.y, sacc);
          sacc = fmaf(tanh_(a0.z + h0.z), v0.z, sacc);
          sacc = fmaf(tanh_(a0.w + h0.w), v0.w, sacc);
          sacc = fmaf(tanh_(a1.x + h1.x), v1.x, sacc);
          sacc = fmaf(tanh_(a1.y + h1.y), v1.y, sacc);
          sacc = fmaf(tanh_(a1.z + h1.z), v1.z, sacc);
          sacc = fmaf(tanh_(a1.w + h1.w), v1.w, sacc);
        }
        sacc += dppf<QP1>(sacc); sacc += dppf<QP2>(sacc); sacc += dppf<HM>(sacc);
        float raw = __shfl(sacc, lane << 3);      // group sums -> lanes 0..7
        int sel = doSample(L, keyk, 0, raw, out + s * 20 + (L - 2) * 4 + t * 2);
        keyk++;
        srcSlot = 6 + sel;                        // x = anchors[index]
      }
      for (int t = 0; t < 2; ++t) {               // 2 op samples
        lstm();
        float a0 = 0, a1 = 0, a2 = 0, a3 = 0;
        const float4* wq = reinterpret_cast<const float4*>(wsoftL + (lane & 7) * 68);
#pragma unroll 4
        for (int c4 = 0; c4 < 16; ++c4) {
          float4 w = wq[c4];
          float4 hv = hU[c4];
          a0 = fmaf(w.x, hv.x, a0);
          a1 = fmaf(w.y, hv.y, a1);
          a2 = fmaf(w.z, hv.z, a2);
          a3 = fmaf(w.w, hv.w, a3);
        }
        float raw = (a0 + a1) + (a2 + a3) + bsoftL[lane & 7];
        int sel = doSample(5, keyk, (s == 0) ? 1 : 2, raw,
                           out + s * 20 + (L - 2) * 4 + t * 2 + 1);
        keyk++;
        srcSlot = 1 + sel;                        // x = embed[op+1]
      }
      lstm();                                     // anchor step
      aw1sL[L * 68 + lane] = matvec(attn1L);
      anchorPre(6 + L);
      srcSlot = 0;                                // x = embed[0]
    }
  }

  if (lane == 0) { out[40] = lp; out[41] = ent; }
}

extern "C" void kernel_launch(void* const* d_in, const int* in_sizes, int n_in,
                              void* d_out, int out_size, void* d_ws, size_t ws_size,
                              hipStream_t stream) {
  (void)in_sizes; (void)n_in; (void)out_size; (void)d_ws; (void)ws_size;
  nas_controller<<<1, NT, 0, stream>>>(
      (const float*)d_in[0],  // embed
      (const float*)d_in[1],  // w_ih
      (const float*)d_in[2],  // w_hh
      (const float*)d_in[3],  // b_ih
      (const float*)d_in[4],  // b_hh
      (const float*)d_in[5],  // w_soft
      (const float*)d_in[6],  // b_soft
      (const float*)d_in[7],  // b_soft_no_learn
      (const float*)d_in[8],  // w_attn1
      (const float*)d_in[9],  // w_attn2
      (const float*)d_in[10], // v_attn
      (const int*)d_in[11],   // seed
      (float*)d_out);
}

// Round 8
// 93.454 us; speedup vs baseline: 2.1527x; 1.7133x over previous
//
#include <hip/hip_runtime.h>
#include <cstdint>

// 1 = fast transcendentals. Set 0 to restore libm path if arcs flip.
#ifndef FASTMATH
#define FASTMATH 1
#endif

#define NT 256

__device__ __forceinline__ uint32_t rotl32_(uint32_t v, int d) {
  return (v << d) | (v >> (32 - d));
}

// Threefry-2x32, 20 rounds, JAX partitionable-mode semantics.
__device__ __forceinline__ void tf2x32(uint32_t k0, uint32_t k1,
                                       uint32_t x0, uint32_t x1,
                                       uint32_t& o0, uint32_t& o1) {
  const uint32_t k2 = k0 ^ k1 ^ 0x1BD11BDAu;
  x0 += k0; x1 += k1;
#define TF4(a,b,c,d) \
  x0 += x1; x1 = rotl32_(x1,a); x1 ^= x0; \
  x0 += x1; x1 = rotl32_(x1,b); x1 ^= x0; \
  x0 += x1; x1 = rotl32_(x1,c); x1 ^= x0; \
  x0 += x1; x1 = rotl32_(x1,d); x1 ^= x0;
  TF4(13,15,26,6)
  x0 += k1; x1 += k2 + 1u;
  TF4(17,29,16,24)
  x0 += k2; x1 += k0 + 2u;
  TF4(13,15,26,6)
  x0 += k0; x1 += k1 + 3u;
  TF4(17,29,16,24)
  x0 += k1; x1 += k2 + 4u;
  TF4(13,15,26,6)
  x0 += k2; x1 += k0 + 5u;
#undef TF4
  o0 = x0; o1 = x1;
}

#if FASTMATH
__device__ __forceinline__ float tanh_(float x) {
  float e = __expf(2.0f * x);
  return 1.0f - __fdividef(2.0f, e + 1.0f);
}
__device__ __forceinline__ float sig_(float x) {
  return __fdividef(1.0f, 1.0f + __expf(-x));
}
#define log_ __logf
#define exp_ __expf
#else
__device__ __forceinline__ float tanh_(float x) { return tanhf(x); }
__device__ __forceinline__ float sig_(float x) { return 0.5f * tanhf(0.5f * x) + 0.5f; }
#define log_ logf
#define exp_ expf
#endif

// DPP helpers (full row/bank masks, bound_ctrl=1). Pure lane permutes.
template <int CTRL>
__device__ __forceinline__ float dppf(float x) {
  return __int_as_float(__builtin_amdgcn_update_dpp(
      0, __float_as_int(x), CTRL, 0xF, 0xF, true));
}
template <int CTRL>
__device__ __forceinline__ int dppi(int x) {
  return __builtin_amdgcn_update_dpp(0, x, CTRL, 0xF, 0xF, true);
}
constexpr int QP1 = 0xB1;   // quad_perm [1,0,3,2] : lane^1
constexpr int QP2 = 0x4E;   // quad_perm [2,3,0,1] : lane^2
constexpr int HM  = 0x141;  // row_half_mirror     : lane^7

__device__ __forceinline__ float rl(float v, int l) {
  return __int_as_float(__builtin_amdgcn_readlane(__float_as_int(v), l));
}

__global__ __launch_bounds__(NT, 1)
void nas_controller(const float* __restrict__ embed,
                    const float* __restrict__ w_ih,
                    const float* __restrict__ w_hh,
                    const float* __restrict__ b_ih,
                    const float* __restrict__ b_hh,
                    const float* __restrict__ w_soft,
                    const float* __restrict__ b_soft,
                    const float* __restrict__ b_soft_nl,
                    const float* __restrict__ w_attn1,
                    const float* __restrict__ w_attn2,
                    const float* __restrict__ v_attn,
                    const int* __restrict__ seedp,
                    float* __restrict__ out) {
  const int tid  = threadIdx.x;
  const int lane = tid & 63;
  const int wid  = tid >> 6;   // wave = gate: 0:i 1:f 2:g 3:o

  __shared__ __align__(16) float wihL[16384];    // W_ih 256 rows, XOR-swizzled (64KB)
  __shared__ __align__(16) float attn1L[4096];   // 64x16 float4, XOR-swizzled
  __shared__ __align__(16) float attn2L[4096];
  __shared__ __align__(16) float wsoftL[8 * 68]; // padded rows
  __shared__ __align__(16) float vaL[64];
  __shared__ __align__(16) float preG[4][13 * 64]; // per-GATE pre (wave-local!)
  __shared__ __align__(16) float aw1sL[8 * 68];  // anchor attn1 products (wave0-local)
  __shared__ __align__(16) float hw2L[64];
  __shared__ __align__(16) float hB[64];         // h state (uniform broadcast reads)
  __shared__ __align__(16) float nlL[4][64];     // per-gate nonlinearity
  __shared__ float gL[320];                      // precomputed gumbels
  __shared__ float bsoftL[8], bnlL[8];
  __shared__ int   seliL;

  // ---- W_hh gate block -> registers (64 VGPRs/lane, the r3-proven budget) ----
  float4 wreg[16];
  {
    const float4* p = reinterpret_cast<const float4*>(w_hh);
#pragma unroll
    for (int k = 0; k < 16; ++k) wreg[k] = p[(wid * 64 + lane) * 16 + k];
  }

  // ---- staging (all 4 waves) ----
  {
    const float4* gih = reinterpret_cast<const float4*>(w_ih);
    float4* lih = reinterpret_cast<float4*>(wihL);
    for (int i4 = tid; i4 < 4096; i4 += NT) {
      int r = i4 >> 4, c4 = i4 & 15, d = (i4 & ~15) + (c4 ^ (r & 15));
      lih[d] = gih[i4];
    }
    const float4* g1 = reinterpret_cast<const float4*>(w_attn1);
    const float4* g2 = reinterpret_cast<const float4*>(w_attn2);
    float4* l1 = reinterpret_cast<float4*>(attn1L);
    float4* l2 = reinterpret_cast<float4*>(attn2L);
    for (int i4 = tid; i4 < 1024; i4 += NT) {
      int r = i4 >> 4, c4 = i4 & 15, d = (i4 & ~15) + (c4 ^ (r & 15));
      l1[d] = g1[i4];
      l2[d] = g2[i4];
    }
  }
  for (int i = tid; i < 544; i += NT) {
    int r = i / 68, c = i % 68;
    wsoftL[i] = (r < 5 && c < 64) ? w_soft[r * 64 + c] : 0.f;
    aw1sL[i] = 0.f;
  }
  if (tid < 64) { vaL[tid] = v_attn[tid]; hB[tid] = 0.f; }
  if (tid < 8) {
    bsoftL[tid] = (tid < 5) ? b_soft[tid] : 0.f;
    bnlL[tid]   = (tid < 5) ? b_soft_nl[tid] : 0.f;
  }
  preG[wid][6 * 64 + lane] = 0.f;   // warmup anchors are zeros
  preG[wid][7 * 64 + lane] = 0.f;

  // Gumbels for all 2x20x8 candidates (data-independent, off the chain).
  for (int t = tid; t < 320; t += NT) {
    int s_ = (t >= 160) ? 1 : 0;
    int rem = t - s_ * 160;
    int k = rem >> 3, i = rem & 7;
    uint32_t a, b, ka, kb, o0, o1;
    tf2x32(0u, (uint32_t)seedp[0], 0u, (uint32_t)s_, a, b);  // split(root)[s]
    tf2x32(a, b, 0u, (uint32_t)k, ka, kb);                   // split(k_s,20)[k]
    tf2x32(ka, kb, 0u, (uint32_t)i, o0, o1);                 // random_bits
    uint32_t bits = o0 ^ o1;
    const float TINY = 1.1754943508222875e-38f;
    float uu = __uint_as_float((bits >> 9) | 0x3f800000u) - 1.0f;
    uu = uu * (1.0f - TINY) + TINY;
    uu = fmaxf(TINY, uu);
    gL[t] = -log_(-log_(uu));
  }

  __syncthreads();

  // W_ih(gate) @ embed[e] for slots 0..5, from swizzled LDS; wave-local output.
  {
    const float4* q = reinterpret_cast<const float4*>(wihL);
    const int rbase = (wid * 64 + lane) << 4;
    for (int e = 0; e < 6; ++e) {
      float ew = embed[e * 64 + lane];
      float a0 = 0, a1 = 0, a2 = 0, a3 = 0;
#pragma unroll
      for (int c4 = 0; c4 < 16; ++c4) {
        float4 w = q[rbase + (c4 ^ (lane & 15))];
        a0 = fmaf(w.x, rl(ew, 4 * c4 + 0), a0);
        a1 = fmaf(w.y, rl(ew, 4 * c4 + 1), a1);
        a2 = fmaf(w.z, rl(ew, 4 * c4 + 2), a2);
        a3 = fmaf(w.w, rl(ew, 4 * c4 + 3), a3);
      }
      preG[wid][e * 64 + lane] = (a0 + a1) + (a2 + a3);
    }
  }

  __syncthreads();

  const float bias_w = b_ih[wid * 64 + lane] + b_hh[wid * 64 + lane];
  float creg = 0.f, lp = 0.f, ent = 0.f;   // creg replicated in all 4 waves
  int srcSlot = 0, sIdx = 0;
  const float4* hU = reinterpret_cast<const float4*>(hB);  // uniform broadcasts

  // One LSTM step: each wave computes ITS gate (64 FMA), combine via LDS.
  auto lstm = [&]() {
    float pre = preG[wid][srcSlot * 64 + lane];
    float a0 = 0, a1 = 0, a2 = 0, a3 = 0;
#pragma unroll
    for (int c4 = 0; c4 < 16; ++c4) {
      float4 hv = hU[c4];                    // uniform-address broadcast
      float4 w  = wreg[c4];                  // register-resident gate row
      a0 = fmaf(w.x, hv.x, a0);
      a1 = fmaf(w.y, hv.y, a1);
      a2 = fmaf(w.z, hv.z, a2);
      a3 = fmaf(w.w, hv.w, a3);
    }
    float gsum = (a0 + a1) + (a2 + a3) + pre + bias_w;
    float nl = (wid == 2) ? tanh_(gsum) : sig_(gsum);
    nlL[wid][lane] = nl;
    __syncthreads();
    float ni = nlL[0][lane], nf = nlL[1][lane], ng = nlL[2][lane], no_ = nlL[3][lane];
    float c2 = nf * creg + ni * ng;          // all waves: identical result
    float h2 = no_ * tanh_(c2);
    creg = c2;
    if (wid == 3) hB[lane] = h2;
    __syncthreads();
  };

  // dst[lane] = dot(W[lane,:], h). Swizzled LDS weights. (wave0 only)
  auto matvec = [&](const float* W) -> float {
    const float4* w4 = reinterpret_cast<const float4*>(W);
    float a0 = 0, a1 = 0, a2 = 0, a3 = 0;
#pragma unroll
    for (int c4 = 0; c4 < 16; ++c4) {
      float4 w = w4[(lane << 4) + (c4 ^ (lane & 15))];
      float4 hv = hU[c4];
      a0 = fmaf(w.x, hv.x, a0);
      a1 = fmaf(w.y, hv.y, a1);
      a2 = fmaf(w.z, hv.z, a2);
      a3 = fmaf(w.w, hv.w, a3);
    }
    return (a0 + a1) + (a2 + a3);
  };

  // W_ih(gate) @ h (new anchor) from LDS; wave-local pre write. (all waves)
  auto anchorPre = [&](int slot) {
    const float4* q = reinterpret_cast<const float4*>(wihL);
    const int rbase = (wid * 64 + lane) << 4;
    float a0 = 0, a1 = 0, a2 = 0, a3 = 0;
#pragma unroll
    for (int c4 = 0; c4 < 16; ++c4) {
      float4 w = q[rbase + (c4 ^ (lane & 15))];
      float4 hv = hU[c4];
      a0 = fmaf(w.x, hv.x, a0);
      a1 = fmaf(w.y, hv.y, a1);
      a2 = fmaf(w.z, hv.z, a2);
      a3 = fmaf(w.w, hv.w, a3);
    }
    preG[wid][slot * 64 + lane] = (a0 + a1) + (a2 + a3);
  };

  // Gumbel-max categorical + log_prob/entropy (wave0 only; lane i = cand i).
  auto doSample = [&](int n, int k, int mode, float raw, float* op) {
    float l;
    if (lane < n) {
      if (mode == 0) l = raw / 5.0f + 1.1f * tanh_(raw);
      else {
        l = (float)(1.1 / 2.5) * tanh_(raw / 5.0f);
        if (mode == 1) l += bnlL[lane];
      }
    } else l = -INFINITY;
    float g = (lane < n) ? gL[sIdx * 160 + k * 8 + lane] : 0.f;
    float v = (lane < n) ? (l + g) : -INFINITY;
    int bi = lane & 7;
    float lw = l;
#define ARGSTEP(C) { float ov = dppf<C>(v), ol = dppf<C>(lw); int oi = dppi<C>(bi); \
    bool tk = (ov > v) || (ov == v && oi < bi); if (tk) { v = ov; lw = ol; bi = oi; } }
    ARGSTEP(QP1) ARGSTEP(QP2) ARGSTEP(HM)
#undef ARGSTEP
    float mx = l;
    mx = fmaxf(mx, dppf<QP1>(mx)); mx = fmaxf(mx, dppf<QP2>(mx)); mx = fmaxf(mx, dppf<HM>(mx));
    float e = (lane < n) ? exp_(l - mx) : 0.f;
    float ss = e; ss += dppf<QP1>(ss); ss += dppf<QP2>(ss); ss += dppf<HM>(ss);
    float lse = log_(ss);
    float lpi = l - mx - lse;
    float ec = (lane < n) ? lpi * exp_(lpi) : 0.f;
    ec += dppf<QP1>(ec); ec += dppf<QP2>(ec); ec += dppf<HM>(ec);
    if (lane == 0) {
      lp  += -(lw - mx - lse);
      ent += -ec;
      seliL = bi;
      op[0] = (float)bi;
    }
  };

  for (int s = 0; s < 2; ++s) {
    sIdx = s;
    srcSlot = 0;
    for (int w = 0; w < 2; ++w) {                 // warmup anchors (zeros)
      lstm();
      if (wid == 0) aw1sL[w * 68 + lane] = matvec(attn1L);
    }
    int keyk = 0;
    for (int L = 2; L <= 6; ++L) {
      for (int t = 0; t < 2; ++t) {               // 2 index samples
        lstm();
        if (wid == 0) {
          hw2L[lane] = matvec(attn2L);
          const int r8 = lane >> 3, j = lane & 7;
          float sacc = 0.f;
          {
            const float4* aw = reinterpret_cast<const float4*>(aw1sL + r8 * 68 + j * 8);
            const float4* hq = reinterpret_cast<const float4*>(hw2L + j * 8);
            const float4* vq = reinterpret_cast<const float4*>(vaL + j * 8);
            float4 a0 = aw[0], a1 = aw[1], h0 = hq[0], h1 = hq[1], v0 = vq[0], v1 = vq[1];
            sacc = fmaf(tanh_(a0.x + h0.x), v0.x, sacc);
            sacc = fmaf(tanh_(a0.y + h0.y), v0.y, sacc);
            sacc = fmaf(tanh_(a0.z + h0.z), v0.z, sacc);
            sacc = fmaf(tanh_(a0.w + h0.w), v0.w, sacc);
            sacc = fmaf(tanh_(a1.x + h1.x), v1.x, sacc);
            sacc = fmaf(tanh_(a1.y + h1.y), v1.y, sacc);
            sacc = fmaf(tanh_(a1.z + h1.z), v1.z, sacc);
            sacc = fmaf(tanh_(a1.w + h1.w), v1.w, sacc);
          }
          sacc += dppf<QP1>(sacc); sacc += dppf<QP2>(sacc); sacc += dppf<HM>(sacc);
          float raw = __shfl(sacc, lane << 3);    // group sums -> lanes 0..7
          doSample(L, keyk, 0, raw, out + s * 20 + (L - 2) * 4 + t * 2);
        }
        keyk++;
        __syncthreads();
        srcSlot = 6 + seliL;                      // x = anchors[index]
      }
      for (int t = 0; t < 2; ++t) {               // 2 op samples
        lstm();
        if (wid == 0) {
          float a0 = 0, a1 = 0, a2 = 0, a3 = 0;
          const float4* wq = reinterpret_cast<const float4*>(wsoftL + (lane & 7) * 68);
#pragma unroll
          for (int c4 = 0; c4 < 16; ++c4) {
            float4 w = wq[c4];
            float4 hv = hU[c4];
            a0 = fmaf(w.x, hv.x, a0);
            a1 = fmaf(w.y, hv.y, a1);
            a2 = fmaf(w.z, hv.z, a2);
            a3 = fmaf(w.w, hv.w, a3);
          }
          float raw = (a0 + a1) + (a2 + a3) + bsoftL[lane & 7];
          doSample(5, keyk, (s == 0) ? 1 : 2, raw,
                   out + s * 20 + (L - 2) * 4 + t * 2 + 1);
        }
        keyk++;
        __syncthreads();
        srcSlot = 1 + seliL;                      // x = embed[op+1]
      }
      lstm();                                     // anchor step
      if (wid == 0) aw1sL[L * 68 + lane] = matvec(attn1L);
      anchorPre(6 + L);                           // all waves, wave-local
      srcSlot = 0;                                // x = embed[0]
    }
  }

  if (tid == 0) { out[40] = lp; out[41] = ent; }
}

extern "C" void kernel_launch(void* const* d_in, const int* in_sizes, int n_in,
                              void* d_out, int out_size, void* d_ws, size_t ws_size,
                              hipStream_t stream) {
  (void)in_sizes; (void)n_in; (void)out_size; (void)d_ws; (void)ws_size;
  nas_controller<<<1, NT, 0, stream>>>(
      (const float*)d_in[0],  // embed
      (const float*)d_in[1],  // w_ih
      (const float*)d_in[2],  // w_hh
      (const float*)d_in[3],  // b_ih
      (const float*)d_in[4],  // b_hh
      (const float*)d_in[5],  // w_soft
      (const float*)d_in[6],  // b_soft
      (const float*)d_in[7],  // b_soft_no_learn
      (const float*)d_in[8],  // w_attn1
      (const float*)d_in[9],  // w_attn2
      (const float*)d_in[10], // v_attn
      (const int*)d_in[11],   // seed
      (float*)d_out);
}